// Round 3
// baseline (279.595 us; speedup 1.0000x reference)
//
#include <hip/hip_runtime.h>

// ---------------------------------------------------------------------------
// GCN 2-layer encoder for MI355X.
//   bin (per-XCD-region append) -> bucketize (LDS hist+scan+scatter, emits dinv/off2)
//   -> GEMM1(->bf16,*dinv) -> AGG1(+b1,relu) -> GEMM2(->bf16,*dinv) -> AGG2(+b2)
// out[r] = dinv[r] * (sum_{e: row=r} hs[col_e] + hs[r]) + b   with hs = (X@W)*dinv
// hs tables stored bf16 to halve gather traffic; all accumulation in f32.
// CSR is segmented per 256-node bucket (base b*8192) -- no global scan needed.
// ---------------------------------------------------------------------------

#define REG_CAP 1024           // entries per (bucket, g) region; mean ~512
#define BUCKET_CAP 8192        // 8 regions * 1024

__device__ __forceinline__ float bf2f(unsigned int u16) {
    return __uint_as_float(u16 << 16);
}
__device__ __forceinline__ unsigned int f2bf_rne(float f) {
    unsigned int u = __float_as_uint(f);
    return (u + 0x7fffu + ((u >> 16) & 1u)) >> 16;
}
__device__ __forceinline__ unsigned int pack2bf(float a, float b) {
    return f2bf_rne(a) | (f2bf_rne(b) << 16);
}

// Append (rlocal | col<<8) into region (row>>8, blockIdx&7). The &7 g-split
// makes same-region appends come from (heuristically) one XCD -> no line thrash.
__global__ void bin_kernel(const int* __restrict__ row, const int* __restrict__ col, int E,
                           int* __restrict__ cur, unsigned int* __restrict__ bucket) {
    const int g = blockIdx.x & 7;
    int i = blockIdx.x * blockDim.x + threadIdx.x;
    int stride = gridDim.x * blockDim.x;
    for (; i < E; i += stride) {
        int r = row[i];
        int reg = (r >> 8) * 8 + g;
        int pos = atomicAdd(&cur[reg], 1);
        if (pos < REG_CAP)
            bucket[(reg << 10) + pos] = (unsigned)(r & 255) | ((unsigned)col[i] << 8);
    }
}

// One block per bucket (256 nodes). LDS: stage entries, histogram, exclusive
// scan, emit dinv/off2, scatter cols in place (block-exclusive 32KB window).
__global__ __launch_bounds__(256) void bucketize_kernel(
    const int* __restrict__ cur, unsigned int* __restrict__ bucket,
    float* __restrict__ dinv, int2* __restrict__ off2, int N)
{
    __shared__ unsigned int ent[BUCKET_CAP];   // 32KB
    __shared__ int hist[256], scn[256], cnt2[256], mreg[8];
    const int b = blockIdx.x, t = threadIdx.x;
    const int n0 = b * 256;

    if (t < 8) mreg[t] = min(cur[b * 8 + t], REG_CAP);
    hist[t] = 0;
    cnt2[t] = 0;
    __syncthreads();

    // load entries to LDS + histogram
    for (int g = 0; g < 8; ++g) {
        int m = mreg[g];
        for (int i = t; i < m; i += 256) {
            unsigned int v = bucket[((b * 8 + g) << 10) + i];
            ent[(g << 10) + i] = v;
            atomicAdd(&hist[v & 255u], 1);
        }
    }
    __syncthreads();

    // exclusive scan of hist
    int h = hist[t];
    scn[t] = h;
    __syncthreads();
    #pragma unroll
    for (int d = 1; d < 256; d <<= 1) {
        int xv = (t >= d) ? scn[t - d] : 0;
        __syncthreads();
        scn[t] += xv;
        __syncthreads();
    }
    int base = scn[t] - h;

    int node = n0 + t;
    if (node < N) {
        dinv[node] = rsqrtf((float)(h + 1));   // +1 self loop
        off2[node] = make_int2(b * BUCKET_CAP + base, b * BUCKET_CAP + base + h);
    }
    scn[t] = base;          // own-slot overwrite, publish for scatter
    __syncthreads();

    // scatter cols back into this block's own bucket slice (in place)
    for (int g = 0; g < 8; ++g) {
        int m = mreg[g];
        for (int i = t; i < m; i += 256) {
            unsigned int v = ent[(g << 10) + i];
            int r = v & 255u;
            int slot = atomicAdd(&cnt2[r], 1);
            bucket[b * BUCKET_CAP + scn[r] + slot] = v >> 8;   // col
        }
    }
}

// C = X(Nx128) @ W(128xCOUT), scaled by dinv[row], stored bf16. 64x64 tile.
__global__ __launch_bounds__(256) void gemm_scale_kernel(
    const float* __restrict__ X, const float* __restrict__ W,
    const float* __restrict__ dinv, unsigned short* __restrict__ out, int N, int COUT)
{
    __shared__ float Ws[128 * 64];   // full K for this 64-col tile
    __shared__ float As[16 * 68];    // 16 k x 64 rows, padded to 68

    const int t = threadIdx.x;
    const int row0 = blockIdx.x * 64;
    const int c0 = blockIdx.y * 64;

    for (int idx = t; idx < 128 * 64; idx += 256) {
        int k = idx >> 6, c = idx & 63;
        Ws[idx] = W[k * COUT + c0 + c];
    }

    const int ty = t >> 4, tx = t & 15;        // compute mapping: 4 rows x 4 cols
    const int m = t >> 2;                      // 0..63 staging row
    const int ksub = (t & 3) * 4;              // 0,4,8,12 staging k
    const int row_l = row0 + m;

    float acc[4][4] = {};
    for (int kt = 0; kt < 8; ++kt) {
        __syncthreads();
        float4 a4 = make_float4(0.f, 0.f, 0.f, 0.f);
        if (row_l < N)
            a4 = *(const float4*)&X[(size_t)row_l * 128 + kt * 16 + ksub];
        As[(ksub + 0) * 68 + m] = a4.x;
        As[(ksub + 1) * 68 + m] = a4.y;
        As[(ksub + 2) * 68 + m] = a4.z;
        As[(ksub + 3) * 68 + m] = a4.w;
        __syncthreads();
        #pragma unroll
        for (int kk = 0; kk < 16; ++kk) {
            float4 a = *(const float4*)&As[kk * 68 + ty * 4];
            float4 w = *(const float4*)&Ws[(kt * 16 + kk) * 64 + tx * 4];
            acc[0][0] += a.x * w.x; acc[0][1] += a.x * w.y; acc[0][2] += a.x * w.z; acc[0][3] += a.x * w.w;
            acc[1][0] += a.y * w.x; acc[1][1] += a.y * w.y; acc[1][2] += a.y * w.z; acc[1][3] += a.y * w.w;
            acc[2][0] += a.z * w.x; acc[2][1] += a.z * w.y; acc[2][2] += a.z * w.z; acc[2][3] += a.z * w.w;
            acc[3][0] += a.w * w.x; acc[3][1] += a.w * w.y; acc[3][2] += a.w * w.z; acc[3][3] += a.w * w.w;
        }
    }

    #pragma unroll
    for (int i = 0; i < 4; ++i) {
        int r = row0 + ty * 4 + i;
        if (r < N) {
            float s = dinv[r];
            uint2 o;
            o.x = pack2bf(acc[i][0] * s, acc[i][1] * s);
            o.y = pack2bf(acc[i][2] * s, acc[i][3] * s);
            *(uint2*)&out[(size_t)r * COUT + c0 + tx * 4] = o;
        }
    }
}

// AGG layer 1: C=128, one wave per node, lane l owns channels {2l, 2l+1}.
__global__ __launch_bounds__(64) void agg1_kernel(
    const unsigned short* __restrict__ hs, const unsigned int* __restrict__ csr,
    const int2* __restrict__ off2, const float* __restrict__ dinv,
    const float* __restrict__ bias, float* __restrict__ out, int N)
{
    const int n = blockIdx.x;
    const int ch = threadIdx.x * 2;

    unsigned int sv = *(const unsigned int*)&hs[(size_t)n * 128 + ch];  // self loop
    float ax = bf2f(sv & 0xffffu), ay = bf2f(sv >> 16);

    int2 se = off2[n];
    int j = se.x, e = se.y;
    for (; j + 3 < e; j += 4) {
        int c0 = csr[j], c1 = csr[j + 1], c2 = csr[j + 2], c3 = csr[j + 3];
        unsigned int v0 = *(const unsigned int*)&hs[(size_t)c0 * 128 + ch];
        unsigned int v1 = *(const unsigned int*)&hs[(size_t)c1 * 128 + ch];
        unsigned int v2 = *(const unsigned int*)&hs[(size_t)c2 * 128 + ch];
        unsigned int v3 = *(const unsigned int*)&hs[(size_t)c3 * 128 + ch];
        ax += bf2f(v0 & 0xffffu); ay += bf2f(v0 >> 16);
        ax += bf2f(v1 & 0xffffu); ay += bf2f(v1 >> 16);
        ax += bf2f(v2 & 0xffffu); ay += bf2f(v2 >> 16);
        ax += bf2f(v3 & 0xffffu); ay += bf2f(v3 >> 16);
    }
    for (; j < e; ++j) {
        unsigned int v = *(const unsigned int*)&hs[(size_t)csr[j] * 128 + ch];
        ax += bf2f(v & 0xffffu); ay += bf2f(v >> 16);
    }

    float d = dinv[n];
    float2 b = *(const float2*)&bias[ch];
    float2 o;
    o.x = fmaxf(d * ax + b.x, 0.0f);
    o.y = fmaxf(d * ay + b.y, 0.0f);
    *(float2*)&out[(size_t)n * 128 + ch] = o;
}

// AGG layer 2: C=64, one wave per node; half-wave per edge, shfl combine.
__global__ __launch_bounds__(64) void agg2_kernel(
    const unsigned short* __restrict__ hs, const unsigned int* __restrict__ csr,
    const int2* __restrict__ off2, const float* __restrict__ dinv,
    const float* __restrict__ bias, float* __restrict__ out, int N)
{
    const int n = blockIdx.x;
    const int l = threadIdx.x;
    const int half = l >> 5;
    const int ch = (l & 31) * 2;

    int2 se = off2[n];
    int j = se.x, e = se.y;
    float ax = 0.f, ay = 0.f;
    for (; j + 3 < e; j += 4) {
        int c0 = csr[j + half];
        int c1 = csr[j + 2 + half];
        unsigned int v0 = *(const unsigned int*)&hs[(size_t)c0 * 64 + ch];
        unsigned int v1 = *(const unsigned int*)&hs[(size_t)c1 * 64 + ch];
        ax += bf2f(v0 & 0xffffu); ay += bf2f(v0 >> 16);
        ax += bf2f(v1 & 0xffffu); ay += bf2f(v1 >> 16);
    }
    if (j + 1 < e) {
        int c = csr[j + half];
        unsigned int v = *(const unsigned int*)&hs[(size_t)c * 64 + ch];
        ax += bf2f(v & 0xffffu); ay += bf2f(v >> 16);
        j += 2;
    }
    if (j < e && half == 0) {   // odd tail edge: lower half only
        unsigned int v = *(const unsigned int*)&hs[(size_t)csr[j] * 64 + ch];
        ax += bf2f(v & 0xffffu); ay += bf2f(v >> 16);
    }

    ax += __shfl_xor(ax, 32);
    ay += __shfl_xor(ay, 32);

    if (half == 0) {
        unsigned int sv = *(const unsigned int*)&hs[(size_t)n * 64 + ch];  // self loop
        ax += bf2f(sv & 0xffffu); ay += bf2f(sv >> 16);
        float d = dinv[n];
        float2 b = *(const float2*)&bias[ch];
        float2 o;
        o.x = d * ax + b.x;
        o.y = d * ay + b.y;
        *(float2*)&out[(size_t)n * 64 + ch] = o;
    }
}

extern "C" void kernel_launch(void* const* d_in, const int* in_sizes, int n_in,
                              void* d_out, int out_size, void* d_ws, size_t ws_size,
                              hipStream_t stream)
{
    const float* x  = (const float*)d_in[0];
    const int*   ei = (const int*)d_in[1];
    const float* W1 = (const float*)d_in[2];
    const float* b1 = (const float*)d_in[3];
    const float* W2 = (const float*)d_in[4];
    const float* b2 = (const float*)d_in[5];
    float* out = (float*)d_out;

    const int N = in_sizes[0] / 128;          // 50000
    const int E = in_sizes[1] / 2;            // 800000
    const int* row = ei;                       // targets
    const int* col = ei + E;                   // sources
    const int NB = (N + 255) / 256;            // 196 buckets

    // workspace layout (256B aligned)
    char* ws = (char*)d_ws;
    size_t o = 0;
    auto take = [&](size_t bytes) { void* p = ws + o; o = (o + bytes + 255) & ~(size_t)255; return p; };
    int*   cur    = (int*)  take((size_t)NB * 8 * 4);
    unsigned int* bucket = (unsigned int*)take((size_t)NB * BUCKET_CAP * 4);  // entries, then in-place CSR
    float* dinv   = (float*)take((size_t)N * 4);
    int2*  off2   = (int2*) take((size_t)N * 8);
    unsigned short* hs  = (unsigned short*)take((size_t)N * 128 * 2);  // bf16, reused as hs2
    float* a1     = (float*)take((size_t)N * 128 * 4);                  // layer-1 activations f32
    unsigned short* hs2 = hs;                                           // alias: hs dead after agg1

    hipMemsetAsync(cur, 0, (size_t)NB * 8 * 4, stream);
    bin_kernel<<<2048, 256, 0, stream>>>(row, col, E, cur, bucket);
    bucketize_kernel<<<NB, 256, 0, stream>>>(cur, bucket, dinv, off2, N);

    // layer 1: hs = bf16((x @ W1) * dinv) ; a1 = relu(dinv*(sum hs[col] + hs[n]) + b1)
    gemm_scale_kernel<<<dim3((N + 63) / 64, 2), 256, 0, stream>>>(x, W1, dinv, hs, N, 128);
    agg1_kernel<<<N, 64, 0, stream>>>(hs, bucket, off2, dinv, b1, a1, N);

    // layer 2: hs2 = bf16((a1 @ W2) * dinv) ; out = dinv*(sum hs2[col] + hs2[n]) + b2
    gemm_scale_kernel<<<dim3((N + 63) / 64, 1), 256, 0, stream>>>(a1, W2, dinv, hs2, N, 64);
    agg2_kernel<<<N, 64, 0, stream>>>(hs2, bucket, off2, dinv, b2, out, N);
}

// Round 4
// 152.182 us; speedup vs baseline: 1.8372x; 1.8372x over previous
//
#include <hip/hip_runtime.h>

// ---------------------------------------------------------------------------
// GCN 2-layer encoder for MI355X.
//   hist -> scanA -> scanB -> scatter (deterministic counting-scatter, no
//   global atomics) -> bucketize (LDS hist+scan+in-place CSR, emits dinv/off2)
//   -> GEMM1(->bf16,*dinv) -> AGG1(+b1,relu) -> GEMM2(->bf16,*dinv) -> AGG2(+b2)
// out[r] = dinv[r] * (sum_{e: row=r} hs[col_e] + hs[r]) + b   with hs = (X@W)*dinv
// hs tables stored bf16 to halve gather traffic; all accumulation in f32.
// CSR segments are exact-sized per 256-node bucket; off2[n] = (start,end).
// ---------------------------------------------------------------------------

#define CHUNKS 256             // edge chunks (pass-1/pass-2 blocks)

__device__ __forceinline__ float bf2f(unsigned int u16) {
    return __uint_as_float(u16 << 16);
}
__device__ __forceinline__ unsigned int f2bf_rne(float f) {
    unsigned int u = __float_as_uint(f);
    return (u + 0x7fffu + ((u >> 16) & 1u)) >> 16;
}
__device__ __forceinline__ unsigned int pack2bf(float a, float b) {
    return f2bf_rne(a) | (f2bf_rne(b) << 16);
}

// Pass 1: per-chunk bucket histogram (bucket = row>>8). cnt[b*CHUNKS + c].
__global__ __launch_bounds__(256) void hist_kernel(
    const int* __restrict__ row, int E, int CE, int NB, int* __restrict__ cnt)
{
    __shared__ int hist[256];
    const int c = blockIdx.x, t = threadIdx.x;
    hist[t] = 0;
    __syncthreads();
    int s = c * CE, e = min(E, s + CE);
    for (int i = s + t; i < e; i += 256) atomicAdd(&hist[row[i] >> 8], 1);
    __syncthreads();
    if (t < NB) cnt[t * CHUNKS + c] = hist[t];
}

// Per-bucket exclusive scan over chunks (in place); emits bucket totals.
__global__ __launch_bounds__(256) void scanA_kernel(int* __restrict__ cnt, int* __restrict__ tot)
{
    __shared__ int s[256];
    const int b = blockIdx.x, t = threadIdx.x;
    int v = cnt[b * CHUNKS + t];
    s[t] = v; __syncthreads();
    #pragma unroll
    for (int d = 1; d < 256; d <<= 1) {
        int xv = (t >= d) ? s[t - d] : 0;
        __syncthreads();
        s[t] += xv;
        __syncthreads();
    }
    cnt[b * CHUNKS + t] = s[t] - v;
    if (t == 255) tot[b] = s[255];
}

// Scan bucket totals -> bstart[b]; bstart[NB] = E.
__global__ __launch_bounds__(256) void scanB_kernel(
    const int* __restrict__ tot, int* __restrict__ bstart, int NB, int E)
{
    __shared__ int s[256];
    const int t = threadIdx.x;
    int v = (t < NB) ? tot[t] : 0;
    s[t] = v; __syncthreads();
    #pragma unroll
    for (int d = 1; d < 256; d <<= 1) {
        int xv = (t >= d) ? s[t - d] : 0;
        __syncthreads();
        s[t] += xv;
        __syncthreads();
    }
    if (t < NB) bstart[t] = s[t] - v;
    if (t == 0) bstart[NB] = E;
}

// Pass 2: scatter packed (rlocal | col<<8) into exact positions via
// block-private LDS cursors. No global atomics; block-exclusive regions.
__global__ __launch_bounds__(256) void scatter_kernel(
    const int* __restrict__ row, const int* __restrict__ col, int E, int CE, int NB,
    const int* __restrict__ cnt, const int* __restrict__ bstart,
    unsigned int* __restrict__ bucket)
{
    __shared__ int curL[256];
    const int c = blockIdx.x, t = threadIdx.x;
    if (t < NB) curL[t] = bstart[t] + cnt[t * CHUNKS + c];
    __syncthreads();
    int s = c * CE, e = min(E, s + CE);
    for (int i = s + t; i < e; i += 256) {
        int r = row[i];
        int b = r >> 8;
        int pos = atomicAdd(&curL[b], 1);
        bucket[pos] = (unsigned)(r & 255) | ((unsigned)col[i] << 8);
    }
}

// One block per bucket (256 nodes). LDS: stage entries, histogram, exclusive
// scan, emit dinv/off2, scatter cols in place (block-exclusive window).
__global__ __launch_bounds__(256) void bucketize_kernel(
    const int* __restrict__ bstart, unsigned int* __restrict__ bucket,
    float* __restrict__ dinv, int2* __restrict__ off2, int N)
{
    __shared__ unsigned int ent[8192];   // 32KB; mean bucket ~4096, 64 sd margin
    __shared__ int hist[256], scn[256], cnt2[256];
    const int b = blockIdx.x, t = threadIdx.x;
    const int n0 = b * 256;

    hist[t] = 0;
    cnt2[t] = 0;
    __syncthreads();

    const int bs = bstart[b], be = bstart[b + 1];
    const int m = min(be - bs, 8192);

    for (int i = t; i < m; i += 256) {
        unsigned int v = bucket[bs + i];
        ent[i] = v;
        atomicAdd(&hist[v & 255u], 1);
    }
    __syncthreads();

    // exclusive scan of hist
    int h = hist[t];
    scn[t] = h;
    __syncthreads();
    #pragma unroll
    for (int d = 1; d < 256; d <<= 1) {
        int xv = (t >= d) ? scn[t - d] : 0;
        __syncthreads();
        scn[t] += xv;
        __syncthreads();
    }
    int base = scn[t] - h;

    int node = n0 + t;
    if (node < N) {
        dinv[node] = rsqrtf((float)(h + 1));   // +1 self loop
        off2[node] = make_int2(bs + base, bs + base + h);
    }
    scn[t] = base;          // publish for scatter
    __syncthreads();

    // scatter cols back into this bucket's own slice (in place; ent holds all)
    for (int i = t; i < m; i += 256) {
        unsigned int v = ent[i];
        int r = v & 255u;
        int slot = atomicAdd(&cnt2[r], 1);
        bucket[bs + scn[r] + slot] = v >> 8;   // col
    }
}

// C = X(Nx128) @ W(128xCOUT), scaled by dinv[row], stored bf16. 64x64 tile.
__global__ __launch_bounds__(256) void gemm_scale_kernel(
    const float* __restrict__ X, const float* __restrict__ W,
    const float* __restrict__ dinv, unsigned short* __restrict__ out, int N, int COUT)
{
    __shared__ float Ws[128 * 64];   // full K for this 64-col tile
    __shared__ float As[16 * 68];    // 16 k x 64 rows, padded to 68

    const int t = threadIdx.x;
    const int row0 = blockIdx.x * 64;
    const int c0 = blockIdx.y * 64;

    for (int idx = t; idx < 128 * 64; idx += 256) {
        int k = idx >> 6, c = idx & 63;
        Ws[idx] = W[k * COUT + c0 + c];
    }

    const int ty = t >> 4, tx = t & 15;        // compute mapping: 4 rows x 4 cols
    const int m = t >> 2;                      // 0..63 staging row
    const int ksub = (t & 3) * 4;              // 0,4,8,12 staging k
    const int row_l = row0 + m;

    float acc[4][4] = {};
    for (int kt = 0; kt < 8; ++kt) {
        __syncthreads();
        float4 a4 = make_float4(0.f, 0.f, 0.f, 0.f);
        if (row_l < N)
            a4 = *(const float4*)&X[(size_t)row_l * 128 + kt * 16 + ksub];
        As[(ksub + 0) * 68 + m] = a4.x;
        As[(ksub + 1) * 68 + m] = a4.y;
        As[(ksub + 2) * 68 + m] = a4.z;
        As[(ksub + 3) * 68 + m] = a4.w;
        __syncthreads();
        #pragma unroll
        for (int kk = 0; kk < 16; ++kk) {
            float4 a = *(const float4*)&As[kk * 68 + ty * 4];
            float4 w = *(const float4*)&Ws[(kt * 16 + kk) * 64 + tx * 4];
            acc[0][0] += a.x * w.x; acc[0][1] += a.x * w.y; acc[0][2] += a.x * w.z; acc[0][3] += a.x * w.w;
            acc[1][0] += a.y * w.x; acc[1][1] += a.y * w.y; acc[1][2] += a.y * w.z; acc[1][3] += a.y * w.w;
            acc[2][0] += a.z * w.x; acc[2][1] += a.z * w.y; acc[2][2] += a.z * w.z; acc[2][3] += a.z * w.w;
            acc[3][0] += a.w * w.x; acc[3][1] += a.w * w.y; acc[3][2] += a.w * w.z; acc[3][3] += a.w * w.w;
        }
    }

    #pragma unroll
    for (int i = 0; i < 4; ++i) {
        int r = row0 + ty * 4 + i;
        if (r < N) {
            float s = dinv[r];
            uint2 o;
            o.x = pack2bf(acc[i][0] * s, acc[i][1] * s);
            o.y = pack2bf(acc[i][2] * s, acc[i][3] * s);
            *(uint2*)&out[(size_t)r * COUT + c0 + tx * 4] = o;
        }
    }
}

// AGG layer 1: C=128, one wave per node, lane l owns channels {2l, 2l+1}.
__global__ __launch_bounds__(64) void agg1_kernel(
    const unsigned short* __restrict__ hs, const unsigned int* __restrict__ csr,
    const int2* __restrict__ off2, const float* __restrict__ dinv,
    const float* __restrict__ bias, float* __restrict__ out, int N)
{
    const int n = blockIdx.x;
    const int ch = threadIdx.x * 2;

    unsigned int sv = *(const unsigned int*)&hs[(size_t)n * 128 + ch];  // self loop
    float ax = bf2f(sv & 0xffffu), ay = bf2f(sv >> 16);

    int2 se = off2[n];
    int j = se.x, e = se.y;
    for (; j + 3 < e; j += 4) {
        int c0 = csr[j], c1 = csr[j + 1], c2 = csr[j + 2], c3 = csr[j + 3];
        unsigned int v0 = *(const unsigned int*)&hs[(size_t)c0 * 128 + ch];
        unsigned int v1 = *(const unsigned int*)&hs[(size_t)c1 * 128 + ch];
        unsigned int v2 = *(const unsigned int*)&hs[(size_t)c2 * 128 + ch];
        unsigned int v3 = *(const unsigned int*)&hs[(size_t)c3 * 128 + ch];
        ax += bf2f(v0 & 0xffffu); ay += bf2f(v0 >> 16);
        ax += bf2f(v1 & 0xffffu); ay += bf2f(v1 >> 16);
        ax += bf2f(v2 & 0xffffu); ay += bf2f(v2 >> 16);
        ax += bf2f(v3 & 0xffffu); ay += bf2f(v3 >> 16);
    }
    for (; j < e; ++j) {
        unsigned int v = *(const unsigned int*)&hs[(size_t)csr[j] * 128 + ch];
        ax += bf2f(v & 0xffffu); ay += bf2f(v >> 16);
    }

    float d = dinv[n];
    float2 b = *(const float2*)&bias[ch];
    float2 o;
    o.x = fmaxf(d * ax + b.x, 0.0f);
    o.y = fmaxf(d * ay + b.y, 0.0f);
    *(float2*)&out[(size_t)n * 128 + ch] = o;
}

// AGG layer 2: C=64, one wave per node; half-wave per edge, shfl combine.
__global__ __launch_bounds__(64) void agg2_kernel(
    const unsigned short* __restrict__ hs, const unsigned int* __restrict__ csr,
    const int2* __restrict__ off2, const float* __restrict__ dinv,
    const float* __restrict__ bias, float* __restrict__ out, int N)
{
    const int n = blockIdx.x;
    const int l = threadIdx.x;
    const int half = l >> 5;
    const int ch = (l & 31) * 2;

    int2 se = off2[n];
    int j = se.x, e = se.y;
    float ax = 0.f, ay = 0.f;
    for (; j + 3 < e; j += 4) {
        int c0 = csr[j + half];
        int c1 = csr[j + 2 + half];
        unsigned int v0 = *(const unsigned int*)&hs[(size_t)c0 * 64 + ch];
        unsigned int v1 = *(const unsigned int*)&hs[(size_t)c1 * 64 + ch];
        ax += bf2f(v0 & 0xffffu); ay += bf2f(v0 >> 16);
        ax += bf2f(v1 & 0xffffu); ay += bf2f(v1 >> 16);
    }
    if (j + 1 < e) {
        int c = csr[j + half];
        unsigned int v = *(const unsigned int*)&hs[(size_t)c * 64 + ch];
        ax += bf2f(v & 0xffffu); ay += bf2f(v >> 16);
        j += 2;
    }
    if (j < e && half == 0) {   // odd tail edge: lower half only
        unsigned int v = *(const unsigned int*)&hs[(size_t)csr[j] * 64 + ch];
        ax += bf2f(v & 0xffffu); ay += bf2f(v >> 16);
    }

    ax += __shfl_xor(ax, 32);
    ay += __shfl_xor(ay, 32);

    if (half == 0) {
        unsigned int sv = *(const unsigned int*)&hs[(size_t)n * 64 + ch];  // self loop
        ax += bf2f(sv & 0xffffu); ay += bf2f(sv >> 16);
        float d = dinv[n];
        float2 b = *(const float2*)&bias[ch];
        float2 o;
        o.x = d * ax + b.x;
        o.y = d * ay + b.y;
        *(float2*)&out[(size_t)n * 64 + ch] = o;
    }
}

extern "C" void kernel_launch(void* const* d_in, const int* in_sizes, int n_in,
                              void* d_out, int out_size, void* d_ws, size_t ws_size,
                              hipStream_t stream)
{
    const float* x  = (const float*)d_in[0];
    const int*   ei = (const int*)d_in[1];
    const float* W1 = (const float*)d_in[2];
    const float* b1 = (const float*)d_in[3];
    const float* W2 = (const float*)d_in[4];
    const float* b2 = (const float*)d_in[5];
    float* out = (float*)d_out;

    const int N = in_sizes[0] / 128;          // 50000
    const int E = in_sizes[1] / 2;            // 800000
    const int* row = ei;                       // targets
    const int* col = ei + E;                   // sources
    const int NB = (N + 255) / 256;            // 196 buckets
    const int CE = (E + CHUNKS - 1) / CHUNKS;  // 3125 edges per chunk

    // workspace layout (256B aligned)
    char* ws = (char*)d_ws;
    size_t o = 0;
    auto take = [&](size_t bytes) { void* p = ws + o; o = (o + bytes + 255) & ~(size_t)255; return p; };
    int*   cnt    = (int*)  take((size_t)NB * CHUNKS * 4);   // counts -> exclusive offsets
    int*   tot    = (int*)  take((size_t)NB * 4);
    int*   bstart = (int*)  take((size_t)(NB + 1) * 4);
    unsigned int* bucket = (unsigned int*)take((size_t)E * 4);   // packed entries -> in-place CSR
    float* dinv   = (float*)take((size_t)N * 4);
    int2*  off2   = (int2*) take((size_t)N * 8);
    unsigned short* hs  = (unsigned short*)take((size_t)N * 128 * 2);  // bf16, reused as hs2
    float* a1     = (float*)take((size_t)N * 128 * 4);                  // layer-1 activations f32
    unsigned short* hs2 = hs;                                           // alias: hs dead after agg1

    hist_kernel<<<CHUNKS, 256, 0, stream>>>(row, E, CE, NB, cnt);
    scanA_kernel<<<NB, 256, 0, stream>>>(cnt, tot);
    scanB_kernel<<<1, 256, 0, stream>>>(tot, bstart, NB, E);
    scatter_kernel<<<CHUNKS, 256, 0, stream>>>(row, col, E, CE, NB, cnt, bstart, bucket);
    bucketize_kernel<<<NB, 256, 0, stream>>>(bstart, bucket, dinv, off2, N);

    // layer 1: hs = bf16((x @ W1) * dinv) ; a1 = relu(dinv*(sum hs[col] + hs[n]) + b1)
    gemm_scale_kernel<<<dim3((N + 63) / 64, 2), 256, 0, stream>>>(x, W1, dinv, hs, N, 128);
    agg1_kernel<<<N, 64, 0, stream>>>(hs, bucket, off2, dinv, b1, a1, N);

    // layer 2: hs2 = bf16((a1 @ W2) * dinv) ; out = dinv*(sum hs2[col] + hs2[n]) + b2
    gemm_scale_kernel<<<dim3((N + 63) / 64, 1), 256, 0, stream>>>(a1, W2, dinv, hs2, N, 64);
    agg2_kernel<<<N, 64, 0, stream>>>(hs2, bucket, off2, dinv, b2, out, N);
}

// Round 5
// 123.073 us; speedup vs baseline: 2.2718x; 1.2365x over previous
//
#include <hip/hip_runtime.h>

// ---------------------------------------------------------------------------
// GCN 2-layer encoder for MI355X.
//   hist -> scanA -> scanB -> scatter (deterministic counting-scatter, no
//   global atomics) -> bucketize (LDS hist+scan+in-place CSR, emits dinv/off2)
//   -> wtrans(W1,W2 -> bf16 col-major) -> MFMA-GEMM1(->bf16,*dinv) -> AGG1
//   -> MFMA-GEMM2(->bf16,*dinv) -> AGG2
// out[r] = dinv[r] * (sum_{e: row=r} hs[col_e] + hs[r]) + b   with hs = (X@W)*dinv
// GEMMs use mfma_f32_16x16x32_bf16 (f32 accum); hs tables bf16.
// A/B fragments use the same (lane>>4,elem)->k assignment => permutation-
// invariant in k, so only the C/D layout (HW-verified) must be exact.
// ---------------------------------------------------------------------------

#define CHUNKS 256             // edge chunks (pass-1/pass-2 blocks)

typedef short bf16x8 __attribute__((ext_vector_type(8)));
typedef float f32x4 __attribute__((ext_vector_type(4)));

__device__ __forceinline__ float bf2f(unsigned int u16) {
    return __uint_as_float(u16 << 16);
}
__device__ __forceinline__ unsigned int f2bf_rne(float f) {
    unsigned int u = __float_as_uint(f);
    return (u + 0x7fffu + ((u >> 16) & 1u)) >> 16;
}
__device__ __forceinline__ unsigned int pack2bf(float a, float b) {
    return f2bf_rne(a) | (f2bf_rne(b) << 16);
}

// ------------------------------ CSR build ----------------------------------

__global__ __launch_bounds__(256) void hist_kernel(
    const int* __restrict__ row, int E, int CE, int NB, int* __restrict__ cnt)
{
    __shared__ int hist[256];
    const int c = blockIdx.x, t = threadIdx.x;
    hist[t] = 0;
    __syncthreads();
    int s = c * CE, e = min(E, s + CE);
    for (int i = s + t; i < e; i += 256) atomicAdd(&hist[row[i] >> 8], 1);
    __syncthreads();
    if (t < NB) cnt[t * CHUNKS + c] = hist[t];
}

__global__ __launch_bounds__(256) void scanA_kernel(int* __restrict__ cnt, int* __restrict__ tot)
{
    __shared__ int s[256];
    const int b = blockIdx.x, t = threadIdx.x;
    int v = cnt[b * CHUNKS + t];
    s[t] = v; __syncthreads();
    #pragma unroll
    for (int d = 1; d < 256; d <<= 1) {
        int xv = (t >= d) ? s[t - d] : 0;
        __syncthreads();
        s[t] += xv;
        __syncthreads();
    }
    cnt[b * CHUNKS + t] = s[t] - v;
    if (t == 255) tot[b] = s[255];
}

__global__ __launch_bounds__(256) void scanB_kernel(
    const int* __restrict__ tot, int* __restrict__ bstart, int NB, int E)
{
    __shared__ int s[256];
    const int t = threadIdx.x;
    int v = (t < NB) ? tot[t] : 0;
    s[t] = v; __syncthreads();
    #pragma unroll
    for (int d = 1; d < 256; d <<= 1) {
        int xv = (t >= d) ? s[t - d] : 0;
        __syncthreads();
        s[t] += xv;
        __syncthreads();
    }
    if (t < NB) bstart[t] = s[t] - v;
    if (t == 0) bstart[NB] = E;
}

__global__ __launch_bounds__(256) void scatter_kernel(
    const int* __restrict__ row, const int* __restrict__ col, int E, int CE, int NB,
    const int* __restrict__ cnt, const int* __restrict__ bstart,
    unsigned int* __restrict__ bucket)
{
    __shared__ int curL[256];
    const int c = blockIdx.x, t = threadIdx.x;
    if (t < NB) curL[t] = bstart[t] + cnt[t * CHUNKS + c];
    __syncthreads();
    int s = c * CE, e = min(E, s + CE);
    for (int i = s + t; i < e; i += 256) {
        int r = row[i];
        int b = r >> 8;
        int pos = atomicAdd(&curL[b], 1);
        bucket[pos] = (unsigned)(r & 255) | ((unsigned)col[i] << 8);
    }
}

__global__ __launch_bounds__(256) void bucketize_kernel(
    const int* __restrict__ bstart, unsigned int* __restrict__ bucket,
    float* __restrict__ dinv, int2* __restrict__ off2, int N)
{
    __shared__ unsigned int ent[8192];   // 32KB; mean bucket ~4096
    __shared__ int hist[256], scn[256], cnt2[256];
    const int b = blockIdx.x, t = threadIdx.x;
    const int n0 = b * 256;

    hist[t] = 0;
    cnt2[t] = 0;
    __syncthreads();

    const int bs = bstart[b], be = bstart[b + 1];
    const int m = min(be - bs, 8192);

    for (int i = t; i < m; i += 256) {
        unsigned int v = bucket[bs + i];
        ent[i] = v;
        atomicAdd(&hist[v & 255u], 1);
    }
    __syncthreads();

    int h = hist[t];
    scn[t] = h;
    __syncthreads();
    #pragma unroll
    for (int d = 1; d < 256; d <<= 1) {
        int xv = (t >= d) ? scn[t - d] : 0;
        __syncthreads();
        scn[t] += xv;
        __syncthreads();
    }
    int base = scn[t] - h;

    int node = n0 + t;
    if (node < N) {
        dinv[node] = rsqrtf((float)(h + 1));   // +1 self loop
        off2[node] = make_int2(bs + base, bs + base + h);
    }
    scn[t] = base;
    __syncthreads();

    for (int i = t; i < m; i += 256) {
        unsigned int v = ent[i];
        int r = v & 255u;
        int slot = atomicAdd(&cnt2[r], 1);
        bucket[bs + scn[r] + slot] = v >> 8;   // col
    }
}

// ------------------------------- GEMMs -------------------------------------

// W[k][c] (128 x C, f32) -> Wt[c][k] (bf16)
__global__ __launch_bounds__(256) void wtrans_kernel(
    const float* __restrict__ W, unsigned short* __restrict__ Wt, int C)
{
    int i = blockIdx.x * 256 + threadIdx.x;
    if (i < 128 * C) {
        int k = i / C, c = i - k * C;
        Wt[c * 128 + k] = (unsigned short)f2bf_rne(W[i]);
    }
}

// out[m][c] = bf16( dinv[m] * sum_k bf16(X[m][k]) * Wt[c][k] ),  COUT = CT*64.
// Block: 64 rows x COUT cols, 4 waves (wave w -> cols [w*CT*16, +CT*16)).
// LDS row stride 256B, XOR-swizzle cb ^= (row&7)<<4 on both write and read.
template <int CT>
__global__ __launch_bounds__(256) void gemm_mfma_kernel(
    const float* __restrict__ X, const unsigned short* __restrict__ Wt,
    const float* __restrict__ dinv, unsigned short* __restrict__ out, int N)
{
    constexpr int COUT = CT * 64;
    __shared__ unsigned short As[64 * 128];      // [row][k] bf16, swizzled
    __shared__ unsigned short Bs[COUT * 128];    // [col][k] bf16, swizzled
    __shared__ float dl[64];

    const int t = threadIdx.x;
    const int m0 = blockIdx.x * 64;

    // stage A: read f32, convert RNE, 8B writes
    #pragma unroll
    for (int i = 0; i < 8; ++i) {
        int f = i * 256 + t;              // float4 index into 64x128 f32 tile
        int r = f >> 5, c4 = f & 31;
        int rg = m0 + r;
        float4 v = (rg < N) ? ((const float4*)X)[(size_t)rg * 32 + c4]
                            : make_float4(0.f, 0.f, 0.f, 0.f);
        uint2 p;
        p.x = pack2bf(v.x, v.y);
        p.y = pack2bf(v.z, v.w);
        int cb = c4 * 8;
        *(uint2*)((char*)As + r * 256 + (cb ^ ((r & 7) << 4))) = p;
    }
    // stage B: Wt already bf16 row-major [c][k]; 8B chunks
    #pragma unroll
    for (int i = 0; i < CT * 8; ++i) {
        int f = i * 256 + t;              // uint2 index into COUT x 128 bf16
        int r = f >> 5;
        int cb = (f & 31) * 8;
        uint2 p = ((const uint2*)Wt)[f];
        *(uint2*)((char*)Bs + r * 256 + (cb ^ ((r & 7) << 4))) = p;
    }
    if (t < 64) dl[t] = (m0 + t < N) ? dinv[m0 + t] : 0.f;
    __syncthreads();

    const int w = t >> 6, l = t & 63;
    const int lr = l & 15, lk = l >> 4;

    bf16x8 af[4][4];                       // [mt][kt]
    #pragma unroll
    for (int mt = 0; mt < 4; ++mt)
        #pragma unroll
        for (int kt = 0; kt < 4; ++kt) {
            int r = mt * 16 + lr;
            int cb = kt * 64 + lk * 16;
            af[mt][kt] = *(const bf16x8*)((const char*)As + r * 256 + (cb ^ ((r & 7) << 4)));
        }
    bf16x8 bfr[CT][4];
    #pragma unroll
    for (int ct = 0; ct < CT; ++ct)
        #pragma unroll
        for (int kt = 0; kt < 4; ++kt) {
            int c = w * (CT * 16) + ct * 16 + lr;
            int cb = kt * 64 + lk * 16;
            bfr[ct][kt] = *(const bf16x8*)((const char*)Bs + c * 256 + (cb ^ ((c & 7) << 4)));
        }

    f32x4 acc[4][CT];
    #pragma unroll
    for (int mt = 0; mt < 4; ++mt)
        #pragma unroll
        for (int ct = 0; ct < CT; ++ct)
            acc[mt][ct] = f32x4{0.f, 0.f, 0.f, 0.f};

    #pragma unroll
    for (int kt = 0; kt < 4; ++kt)
        #pragma unroll
        for (int mt = 0; mt < 4; ++mt)
            #pragma unroll
            for (int ct = 0; ct < CT; ++ct)
                acc[mt][ct] = __builtin_amdgcn_mfma_f32_16x16x32_bf16(
                    af[mt][kt], bfr[ct][kt], acc[mt][ct], 0, 0, 0);

    // epilogue: C/D layout col = lane&15, row = (lane>>4)*4 + reg
    #pragma unroll
    for (int mt = 0; mt < 4; ++mt) {
        #pragma unroll
        for (int ct = 0; ct < CT; ++ct) {
            #pragma unroll
            for (int r = 0; r < 4; ++r) {
                int rowl = mt * 16 + lk * 4 + r;
                int grow = m0 + rowl;
                if (grow < N) {
                    int c = w * (CT * 16) + ct * 16 + lr;
                    float v = acc[mt][ct][r] * dl[rowl];
                    out[(size_t)grow * COUT + c] = (unsigned short)f2bf_rne(v);
                }
            }
        }
    }
}

// ------------------------------- AGGs --------------------------------------

// AGG layer 1: C=128, one wave per node, lane l owns channels {2l, 2l+1}.
__global__ __launch_bounds__(64) void agg1_kernel(
    const unsigned short* __restrict__ hs, const unsigned int* __restrict__ csr,
    const int2* __restrict__ off2, const float* __restrict__ dinv,
    const float* __restrict__ bias, float* __restrict__ out, int N)
{
    const int n = blockIdx.x;
    const int ch = threadIdx.x * 2;

    unsigned int sv = *(const unsigned int*)&hs[(size_t)n * 128 + ch];  // self loop
    float ax = bf2f(sv & 0xffffu), ay = bf2f(sv >> 16);

    int2 se = off2[n];
    int j = se.x, e = se.y;
    for (; j + 3 < e; j += 4) {
        int c0 = csr[j], c1 = csr[j + 1], c2 = csr[j + 2], c3 = csr[j + 3];
        unsigned int v0 = *(const unsigned int*)&hs[(size_t)c0 * 128 + ch];
        unsigned int v1 = *(const unsigned int*)&hs[(size_t)c1 * 128 + ch];
        unsigned int v2 = *(const unsigned int*)&hs[(size_t)c2 * 128 + ch];
        unsigned int v3 = *(const unsigned int*)&hs[(size_t)c3 * 128 + ch];
        ax += bf2f(v0 & 0xffffu); ay += bf2f(v0 >> 16);
        ax += bf2f(v1 & 0xffffu); ay += bf2f(v1 >> 16);
        ax += bf2f(v2 & 0xffffu); ay += bf2f(v2 >> 16);
        ax += bf2f(v3 & 0xffffu); ay += bf2f(v3 >> 16);
    }
    for (; j < e; ++j) {
        unsigned int v = *(const unsigned int*)&hs[(size_t)csr[j] * 128 + ch];
        ax += bf2f(v & 0xffffu); ay += bf2f(v >> 16);
    }

    float d = dinv[n];
    float2 b = *(const float2*)&bias[ch];
    float2 o;
    o.x = fmaxf(d * ax + b.x, 0.0f);
    o.y = fmaxf(d * ay + b.y, 0.0f);
    *(float2*)&out[(size_t)n * 128 + ch] = o;
}

// AGG layer 2: C=64, one wave per node; half-wave per edge, shfl combine.
__global__ __launch_bounds__(64) void agg2_kernel(
    const unsigned short* __restrict__ hs, const unsigned int* __restrict__ csr,
    const int2* __restrict__ off2, const float* __restrict__ dinv,
    const float* __restrict__ bias, float* __restrict__ out, int N)
{
    const int n = blockIdx.x;
    const int l = threadIdx.x;
    const int half = l >> 5;
    const int ch = (l & 31) * 2;

    int2 se = off2[n];
    int j = se.x, e = se.y;
    float ax = 0.f, ay = 0.f;
    for (; j + 3 < e; j += 4) {
        int c0 = csr[j + half];
        int c1 = csr[j + 2 + half];
        unsigned int v0 = *(const unsigned int*)&hs[(size_t)c0 * 64 + ch];
        unsigned int v1 = *(const unsigned int*)&hs[(size_t)c1 * 64 + ch];
        ax += bf2f(v0 & 0xffffu); ay += bf2f(v0 >> 16);
        ax += bf2f(v1 & 0xffffu); ay += bf2f(v1 >> 16);
    }
    if (j + 1 < e) {
        int c = csr[j + half];
        unsigned int v = *(const unsigned int*)&hs[(size_t)c * 64 + ch];
        ax += bf2f(v & 0xffffu); ay += bf2f(v >> 16);
        j += 2;
    }
    if (j < e && half == 0) {
        unsigned int v = *(const unsigned int*)&hs[(size_t)csr[j] * 64 + ch];
        ax += bf2f(v & 0xffffu); ay += bf2f(v >> 16);
    }

    ax += __shfl_xor(ax, 32);
    ay += __shfl_xor(ay, 32);

    if (half == 0) {
        unsigned int sv = *(const unsigned int*)&hs[(size_t)n * 64 + ch];  // self loop
        ax += bf2f(sv & 0xffffu); ay += bf2f(sv >> 16);
        float d = dinv[n];
        float2 b = *(const float2*)&bias[ch];
        float2 o;
        o.x = d * ax + b.x;
        o.y = d * ay + b.y;
        *(float2*)&out[(size_t)n * 64 + ch] = o;
    }
}

extern "C" void kernel_launch(void* const* d_in, const int* in_sizes, int n_in,
                              void* d_out, int out_size, void* d_ws, size_t ws_size,
                              hipStream_t stream)
{
    const float* x  = (const float*)d_in[0];
    const int*   ei = (const int*)d_in[1];
    const float* W1 = (const float*)d_in[2];
    const float* b1 = (const float*)d_in[3];
    const float* W2 = (const float*)d_in[4];
    const float* b2 = (const float*)d_in[5];
    float* out = (float*)d_out;

    const int N = in_sizes[0] / 128;          // 50000
    const int E = in_sizes[1] / 2;            // 800000
    const int* row = ei;                       // targets
    const int* col = ei + E;                   // sources
    const int NB = (N + 255) / 256;            // 196 buckets
    const int CE = (E + CHUNKS - 1) / CHUNKS;  // 3125 edges per chunk

    // workspace layout (256B aligned)
    char* ws = (char*)d_ws;
    size_t o = 0;
    auto take = [&](size_t bytes) { void* p = ws + o; o = (o + bytes + 255) & ~(size_t)255; return p; };
    int*   cnt    = (int*)  take((size_t)NB * CHUNKS * 4);
    int*   tot    = (int*)  take((size_t)NB * 4);
    int*   bstart = (int*)  take((size_t)(NB + 1) * 4);
    unsigned int* bucket = (unsigned int*)take((size_t)E * 4);   // packed -> in-place CSR
    float* dinv   = (float*)take((size_t)N * 4);
    int2*  off2   = (int2*) take((size_t)N * 8);
    unsigned short* Wt1 = (unsigned short*)take(128 * 128 * 2);
    unsigned short* Wt2 = (unsigned short*)take(64 * 128 * 2);
    unsigned short* hs  = (unsigned short*)take((size_t)N * 128 * 2);  // bf16, reused as hs2
    float* a1     = (float*)take((size_t)N * 128 * 4);                  // layer-1 acts f32
    unsigned short* hs2 = hs;                                           // alias

    hist_kernel<<<CHUNKS, 256, 0, stream>>>(row, E, CE, NB, cnt);
    scanA_kernel<<<NB, 256, 0, stream>>>(cnt, tot);
    scanB_kernel<<<1, 256, 0, stream>>>(tot, bstart, NB, E);
    scatter_kernel<<<CHUNKS, 256, 0, stream>>>(row, col, E, CE, NB, cnt, bstart, bucket);
    bucketize_kernel<<<NB, 256, 0, stream>>>(bstart, bucket, dinv, off2, N);

    wtrans_kernel<<<(128 * 128 + 255) / 256, 256, 0, stream>>>(W1, Wt1, 128);
    wtrans_kernel<<<(128 * 64 + 255) / 256, 256, 0, stream>>>(W2, Wt2, 64);

    // layer 1
    gemm_mfma_kernel<2><<<(N + 63) / 64, 256, 0, stream>>>(x, Wt1, dinv, hs, N);
    agg1_kernel<<<N, 64, 0, stream>>>(hs, bucket, off2, dinv, b1, a1, N);

    // layer 2
    gemm_mfma_kernel<1><<<(N + 63) / 64, 256, 0, stream>>>(a1, Wt2, dinv, hs2, N);
    agg2_kernel<<<N, 64, 0, stream>>>(hs2, bucket, off2, dinv, b2, out, N);
}

// Round 6
// 114.077 us; speedup vs baseline: 2.4509x; 1.0789x over previous
//
#include <hip/hip_runtime.h>

// ---------------------------------------------------------------------------
// GCN 2-layer encoder for MI355X.
//   hist -> scanA -> scanB -> scatter (deterministic counting-scatter, no
//   global atomics) -> bucketize (LDS hist+scan+in-place CSR, emits dinv/off2)
//   -> wtrans(W1+W2 -> bf16 col-major, one launch)
//   -> MFMA-GEMM1(f32 in ->bf16,*dinv) -> AGG1(+b1,relu -> bf16 a1)
//   -> MFMA-GEMM2(bf16 in ->bf16,*dinv) -> AGG2(+b2 -> f32 out)
// out[r] = dinv[r] * (sum_{e: row=r} hs[col_e] + hs[r]) + b   with hs = (X@W)*dinv
// AGG gathers: 16B/lane, multi-row-per-wave (agg1: 4 rows/instr, agg2: 8),
// cross-group shfl_xor reduce. a1 kept bf16 (identical math: gemm2 would
// RNE-convert anyway).
// ---------------------------------------------------------------------------

#define CHUNKS 256             // edge chunks (pass-1/pass-2 blocks)

typedef short bf16x8 __attribute__((ext_vector_type(8)));
typedef float f32x4 __attribute__((ext_vector_type(4)));

__device__ __forceinline__ float bf2f(unsigned int u16) {
    return __uint_as_float(u16 << 16);
}
__device__ __forceinline__ unsigned int f2bf_rne(float f) {
    unsigned int u = __float_as_uint(f);
    return (u + 0x7fffu + ((u >> 16) & 1u)) >> 16;
}
__device__ __forceinline__ unsigned int pack2bf(float a, float b) {
    return f2bf_rne(a) | (f2bf_rne(b) << 16);
}
__device__ __forceinline__ void add8(float* acc, uint4 p) {
    acc[0] += bf2f(p.x & 0xffffu); acc[1] += bf2f(p.x >> 16);
    acc[2] += bf2f(p.y & 0xffffu); acc[3] += bf2f(p.y >> 16);
    acc[4] += bf2f(p.z & 0xffffu); acc[5] += bf2f(p.z >> 16);
    acc[6] += bf2f(p.w & 0xffffu); acc[7] += bf2f(p.w >> 16);
}

// ------------------------------ CSR build ----------------------------------

__global__ __launch_bounds__(256) void hist_kernel(
    const int* __restrict__ row, int E, int CE, int NB, int* __restrict__ cnt)
{
    __shared__ int hist[256];
    const int c = blockIdx.x, t = threadIdx.x;
    hist[t] = 0;
    __syncthreads();
    int s = c * CE, e = min(E, s + CE);
    for (int i = s + t; i < e; i += 256) atomicAdd(&hist[row[i] >> 8], 1);
    __syncthreads();
    if (t < NB) cnt[t * CHUNKS + c] = hist[t];
}

__global__ __launch_bounds__(256) void scanA_kernel(int* __restrict__ cnt, int* __restrict__ tot)
{
    __shared__ int s[256];
    const int b = blockIdx.x, t = threadIdx.x;
    int v = cnt[b * CHUNKS + t];
    s[t] = v; __syncthreads();
    #pragma unroll
    for (int d = 1; d < 256; d <<= 1) {
        int xv = (t >= d) ? s[t - d] : 0;
        __syncthreads();
        s[t] += xv;
        __syncthreads();
    }
    cnt[b * CHUNKS + t] = s[t] - v;
    if (t == 255) tot[b] = s[255];
}

__global__ __launch_bounds__(256) void scanB_kernel(
    const int* __restrict__ tot, int* __restrict__ bstart, int NB, int E)
{
    __shared__ int s[256];
    const int t = threadIdx.x;
    int v = (t < NB) ? tot[t] : 0;
    s[t] = v; __syncthreads();
    #pragma unroll
    for (int d = 1; d < 256; d <<= 1) {
        int xv = (t >= d) ? s[t - d] : 0;
        __syncthreads();
        s[t] += xv;
        __syncthreads();
    }
    if (t < NB) bstart[t] = s[t] - v;
    if (t == 0) bstart[NB] = E;
}

__global__ __launch_bounds__(256) void scatter_kernel(
    const int* __restrict__ row, const int* __restrict__ col, int E, int CE, int NB,
    const int* __restrict__ cnt, const int* __restrict__ bstart,
    unsigned int* __restrict__ bucket)
{
    __shared__ int curL[256];
    const int c = blockIdx.x, t = threadIdx.x;
    if (t < NB) curL[t] = bstart[t] + cnt[t * CHUNKS + c];
    __syncthreads();
    int s = c * CE, e = min(E, s + CE);
    for (int i = s + t; i < e; i += 256) {
        int r = row[i];
        int b = r >> 8;
        int pos = atomicAdd(&curL[b], 1);
        bucket[pos] = (unsigned)(r & 255) | ((unsigned)col[i] << 8);
    }
}

__global__ __launch_bounds__(256) void bucketize_kernel(
    const int* __restrict__ bstart, unsigned int* __restrict__ bucket,
    float* __restrict__ dinv, int2* __restrict__ off2, int N)
{
    __shared__ unsigned int ent[8192];   // 32KB; mean bucket ~4096
    __shared__ int hist[256], scn[256], cnt2[256];
    const int b = blockIdx.x, t = threadIdx.x;
    const int n0 = b * 256;

    hist[t] = 0;
    cnt2[t] = 0;
    __syncthreads();

    const int bs = bstart[b], be = bstart[b + 1];
    const int m = min(be - bs, 8192);

    for (int i = t; i < m; i += 256) {
        unsigned int v = bucket[bs + i];
        ent[i] = v;
        atomicAdd(&hist[v & 255u], 1);
    }
    __syncthreads();

    int h = hist[t];
    scn[t] = h;
    __syncthreads();
    #pragma unroll
    for (int d = 1; d < 256; d <<= 1) {
        int xv = (t >= d) ? scn[t - d] : 0;
        __syncthreads();
        scn[t] += xv;
        __syncthreads();
    }
    int base = scn[t] - h;

    int node = n0 + t;
    if (node < N) {
        dinv[node] = rsqrtf((float)(h + 1));   // +1 self loop
        off2[node] = make_int2(bs + base, bs + base + h);
    }
    scn[t] = base;
    __syncthreads();

    for (int i = t; i < m; i += 256) {
        unsigned int v = ent[i];
        int r = v & 255u;
        int slot = atomicAdd(&cnt2[r], 1);
        bucket[bs + scn[r] + slot] = v >> 8;   // col
    }
}

// ------------------------------- GEMMs -------------------------------------

// W1[k][c] (128x128) -> Wt1[c][k] bf16 ; W2[k][c] (128x64) -> Wt2[c][k] bf16
__global__ __launch_bounds__(256) void wtrans_kernel(
    const float* __restrict__ W1, const float* __restrict__ W2,
    unsigned short* __restrict__ Wt1, unsigned short* __restrict__ Wt2)
{
    int i = blockIdx.x * 256 + threadIdx.x;
    if (i < 128 * 128) {
        int k = i >> 7, c = i & 127;
        Wt1[c * 128 + k] = (unsigned short)f2bf_rne(W1[i]);
    } else {
        int j = i - 128 * 128;
        if (j < 128 * 64) {
            int k = j >> 6, c = j & 63;
            Wt2[c * 128 + k] = (unsigned short)f2bf_rne(W2[j]);
        }
    }
}

// out[m][c] = bf16( dinv[m] * sum_k bf16(X[m][k]) * Wt[c][k] ),  COUT = CT*64.
// Block: 64 rows x COUT cols, 4 waves. LDS row stride 256B, XOR-swizzle
// cb ^= (row&7)<<4 on both write and read. BF16IN: X already bf16 row-major.
template <int CT, bool BF16IN>
__global__ __launch_bounds__(256) void gemm_mfma_kernel(
    const void* __restrict__ Xv, const unsigned short* __restrict__ Wt,
    const float* __restrict__ dinv, unsigned short* __restrict__ out, int N)
{
    constexpr int COUT = CT * 64;
    __shared__ unsigned short As[64 * 128];      // [row][k] bf16, swizzled
    __shared__ unsigned short Bs[COUT * 128];    // [col][k] bf16, swizzled
    __shared__ float dl[64];

    const int t = threadIdx.x;
    const int m0 = blockIdx.x * 64;

    if (BF16IN) {
        const unsigned short* X = (const unsigned short*)Xv;
        #pragma unroll
        for (int i = 0; i < 4; ++i) {
            int f = i * 256 + t;          // uint4 index into 64x128 bf16 tile
            int r = f >> 4, c16 = f & 15;
            int rg = m0 + r;
            uint4 p = (rg < N) ? ((const uint4*)X)[(size_t)rg * 16 + c16]
                               : make_uint4(0u, 0u, 0u, 0u);
            int cb = c16 * 16;
            *(uint4*)((char*)As + r * 256 + (cb ^ ((r & 7) << 4))) = p;
        }
    } else {
        const float* X = (const float*)Xv;
        #pragma unroll
        for (int i = 0; i < 8; ++i) {
            int f = i * 256 + t;          // float4 index into 64x128 f32 tile
            int r = f >> 5, c4 = f & 31;
            int rg = m0 + r;
            float4 v = (rg < N) ? ((const float4*)X)[(size_t)rg * 32 + c4]
                                : make_float4(0.f, 0.f, 0.f, 0.f);
            uint2 p;
            p.x = pack2bf(v.x, v.y);
            p.y = pack2bf(v.z, v.w);
            int cb = c4 * 8;
            *(uint2*)((char*)As + r * 256 + (cb ^ ((r & 7) << 4))) = p;
        }
    }
    #pragma unroll
    for (int i = 0; i < CT * 8; ++i) {
        int f = i * 256 + t;              // uint2 index into COUT x 128 bf16
        int r = f >> 5;
        int cb = (f & 31) * 8;
        uint2 p = ((const uint2*)Wt)[f];
        *(uint2*)((char*)Bs + r * 256 + (cb ^ ((r & 7) << 4))) = p;
    }
    if (t < 64) dl[t] = (m0 + t < N) ? dinv[m0 + t] : 0.f;
    __syncthreads();

    const int w = t >> 6, l = t & 63;
    const int lr = l & 15, lk = l >> 4;

    bf16x8 af[4][4];                       // [mt][kt]
    #pragma unroll
    for (int mt = 0; mt < 4; ++mt)
        #pragma unroll
        for (int kt = 0; kt < 4; ++kt) {
            int r = mt * 16 + lr;
            int cb = kt * 64 + lk * 16;
            af[mt][kt] = *(const bf16x8*)((const char*)As + r * 256 + (cb ^ ((r & 7) << 4)));
        }
    bf16x8 bfr[CT][4];
    #pragma unroll
    for (int ct = 0; ct < CT; ++ct)
        #pragma unroll
        for (int kt = 0; kt < 4; ++kt) {
            int c = w * (CT * 16) + ct * 16 + lr;
            int cb = kt * 64 + lk * 16;
            bfr[ct][kt] = *(const bf16x8*)((const char*)Bs + c * 256 + (cb ^ ((c & 7) << 4)));
        }

    f32x4 acc[4][CT];
    #pragma unroll
    for (int mt = 0; mt < 4; ++mt)
        #pragma unroll
        for (int ct = 0; ct < CT; ++ct)
            acc[mt][ct] = f32x4{0.f, 0.f, 0.f, 0.f};

    #pragma unroll
    for (int kt = 0; kt < 4; ++kt)
        #pragma unroll
        for (int mt = 0; mt < 4; ++mt)
            #pragma unroll
            for (int ct = 0; ct < CT; ++ct)
                acc[mt][ct] = __builtin_amdgcn_mfma_f32_16x16x32_bf16(
                    af[mt][kt], bfr[ct][kt], acc[mt][ct], 0, 0, 0);

    // epilogue: C/D layout col = lane&15, row = (lane>>4)*4 + reg
    #pragma unroll
    for (int mt = 0; mt < 4; ++mt) {
        #pragma unroll
        for (int ct = 0; ct < CT; ++ct) {
            #pragma unroll
            for (int r = 0; r < 4; ++r) {
                int rowl = mt * 16 + lk * 4 + r;
                int grow = m0 + rowl;
                if (grow < N) {
                    int c = w * (CT * 16) + ct * 16 + lr;
                    float v = acc[mt][ct][r] * dl[rowl];
                    out[(size_t)grow * COUT + c] = (unsigned short)f2bf_rne(v);
                }
            }
        }
    }
}

// ------------------------------- AGGs --------------------------------------

// AGG layer 1: C=128 bf16 rows (256B). Wave per node; lane q=l&15 owns
// channels 8q..8q+7 (16B), group g=l>>4 processes edge j+g (4 rows/instr).
// Output a1 as bf16 (identical math: gemm2 RNE-converts anyway).
__global__ __launch_bounds__(64) void agg1_kernel(
    const unsigned short* __restrict__ hs, const unsigned int* __restrict__ csr,
    const int2* __restrict__ off2, const float* __restrict__ dinv,
    const float* __restrict__ bias, unsigned short* __restrict__ out, int N)
{
    const int n = blockIdx.x;
    const int l = threadIdx.x;
    const int q = l & 15, g = l >> 4;

    float acc[8] = {};
    if (g == 0)                                        // self loop
        add8(acc, *(const uint4*)&hs[(size_t)n * 128 + q * 8]);

    int2 se = off2[n];
    int j = se.x, e = se.y;
    for (; j + 7 < e; j += 8) {
        int c0 = csr[j + g], c1 = csr[j + 4 + g];
        uint4 p0 = *(const uint4*)&hs[(size_t)c0 * 128 + q * 8];
        uint4 p1 = *(const uint4*)&hs[(size_t)c1 * 128 + q * 8];
        add8(acc, p0);
        add8(acc, p1);
    }
    if (j + 3 < e) {
        add8(acc, *(const uint4*)&hs[(size_t)csr[j + g] * 128 + q * 8]);
        j += 4;
    }
    if (g < e - j)
        add8(acc, *(const uint4*)&hs[(size_t)csr[j + g] * 128 + q * 8]);

    #pragma unroll
    for (int i = 0; i < 8; ++i) {
        acc[i] += __shfl_xor(acc[i], 16);
        acc[i] += __shfl_xor(acc[i], 32);
    }

    if (g == 0) {
        float d = dinv[n];
        float4 b0 = ((const float4*)bias)[q * 2];
        float4 b1 = ((const float4*)bias)[q * 2 + 1];
        float v0 = fmaxf(d * acc[0] + b0.x, 0.f), v1 = fmaxf(d * acc[1] + b0.y, 0.f);
        float v2 = fmaxf(d * acc[2] + b0.z, 0.f), v3 = fmaxf(d * acc[3] + b0.w, 0.f);
        float v4 = fmaxf(d * acc[4] + b1.x, 0.f), v5 = fmaxf(d * acc[5] + b1.y, 0.f);
        float v6 = fmaxf(d * acc[6] + b1.z, 0.f), v7 = fmaxf(d * acc[7] + b1.w, 0.f);
        uint4 o;
        o.x = pack2bf(v0, v1); o.y = pack2bf(v2, v3);
        o.z = pack2bf(v4, v5); o.w = pack2bf(v6, v7);
        *(uint4*)&out[(size_t)n * 128 + q * 8] = o;
    }
}

// AGG layer 2: C=64 bf16 rows (128B). Wave per node; lane q=l&7 owns
// channels 8q..8q+7 (16B), group g=l>>3 processes edge j+g (8 rows/instr).
// f32 output (final).
__global__ __launch_bounds__(64) void agg2_kernel(
    const unsigned short* __restrict__ hs, const unsigned int* __restrict__ csr,
    const int2* __restrict__ off2, const float* __restrict__ dinv,
    const float* __restrict__ bias, float* __restrict__ out, int N)
{
    const int n = blockIdx.x;
    const int l = threadIdx.x;
    const int q = l & 7, g = l >> 3;

    float acc[8] = {};
    if (g == 0)                                        // self loop
        add8(acc, *(const uint4*)&hs[(size_t)n * 64 + q * 8]);

    int2 se = off2[n];
    int j = se.x, e = se.y;
    for (; j + 15 < e; j += 16) {
        int c0 = csr[j + g], c1 = csr[j + 8 + g];
        uint4 p0 = *(const uint4*)&hs[(size_t)c0 * 64 + q * 8];
        uint4 p1 = *(const uint4*)&hs[(size_t)c1 * 64 + q * 8];
        add8(acc, p0);
        add8(acc, p1);
    }
    if (j + 7 < e) {
        add8(acc, *(const uint4*)&hs[(size_t)csr[j + g] * 64 + q * 8]);
        j += 8;
    }
    if (g < e - j)
        add8(acc, *(const uint4*)&hs[(size_t)csr[j + g] * 64 + q * 8]);

    #pragma unroll
    for (int i = 0; i < 8; ++i) {
        acc[i] += __shfl_xor(acc[i], 8);
        acc[i] += __shfl_xor(acc[i], 16);
        acc[i] += __shfl_xor(acc[i], 32);
    }

    if (g == 0) {
        float d = dinv[n];
        float4 b0 = ((const float4*)bias)[q * 2];
        float4 b1 = ((const float4*)bias)[q * 2 + 1];
        float4 o0, o1;
        o0.x = d * acc[0] + b0.x; o0.y = d * acc[1] + b0.y;
        o0.z = d * acc[2] + b0.z; o0.w = d * acc[3] + b0.w;
        o1.x = d * acc[4] + b1.x; o1.y = d * acc[5] + b1.y;
        o1.z = d * acc[6] + b1.z; o1.w = d * acc[7] + b1.w;
        *(float4*)&out[(size_t)n * 64 + q * 8] = o0;
        *(float4*)&out[(size_t)n * 64 + q * 8 + 4] = o1;
    }
}

extern "C" void kernel_launch(void* const* d_in, const int* in_sizes, int n_in,
                              void* d_out, int out_size, void* d_ws, size_t ws_size,
                              hipStream_t stream)
{
    const float* x  = (const float*)d_in[0];
    const int*   ei = (const int*)d_in[1];
    const float* W1 = (const float*)d_in[2];
    const float* b1 = (const float*)d_in[3];
    const float* W2 = (const float*)d_in[4];
    const float* b2 = (const float*)d_in[5];
    float* out = (float*)d_out;

    const int N = in_sizes[0] / 128;          // 50000
    const int E = in_sizes[1] / 2;            // 800000
    const int* row = ei;                       // targets
    const int* col = ei + E;                   // sources
    const int NB = (N + 255) / 256;            // 196 buckets
    const int CE = (E + CHUNKS - 1) / CHUNKS;  // 3125 edges per chunk

    // workspace layout (256B aligned)
    char* ws = (char*)d_ws;
    size_t o = 0;
    auto take = [&](size_t bytes) { void* p = ws + o; o = (o + bytes + 255) & ~(size_t)255; return p; };
    int*   cnt    = (int*)  take((size_t)NB * CHUNKS * 4);
    int*   tot    = (int*)  take((size_t)NB * 4);
    int*   bstart = (int*)  take((size_t)(NB + 1) * 4);
    unsigned int* bucket = (unsigned int*)take((size_t)E * 4);   // packed -> in-place CSR
    float* dinv   = (float*)take((size_t)N * 4);
    int2*  off2   = (int2*) take((size_t)N * 8);
    unsigned short* Wt1 = (unsigned short*)take(128 * 128 * 2);
    unsigned short* Wt2 = (unsigned short*)take(64 * 128 * 2);
    unsigned short* hs  = (unsigned short*)take((size_t)N * 128 * 2);  // bf16, reused as hs2
    unsigned short* a1  = (unsigned short*)take((size_t)N * 128 * 2);  // layer-1 acts bf16
    unsigned short* hs2 = hs;                                           // alias

    hist_kernel<<<CHUNKS, 256, 0, stream>>>(row, E, CE, NB, cnt);
    scanA_kernel<<<NB, 256, 0, stream>>>(cnt, tot);
    scanB_kernel<<<1, 256, 0, stream>>>(tot, bstart, NB, E);
    scatter_kernel<<<CHUNKS, 256, 0, stream>>>(row, col, E, CE, NB, cnt, bstart, bucket);
    bucketize_kernel<<<NB, 256, 0, stream>>>(bstart, bucket, dinv, off2, N);

    wtrans_kernel<<<(128 * 128 + 128 * 64 + 255) / 256, 256, 0, stream>>>(W1, W2, Wt1, Wt2);

    // layer 1
    gemm_mfma_kernel<2, false><<<(N + 63) / 64, 256, 0, stream>>>(x, Wt1, dinv, hs, N);
    agg1_kernel<<<N, 64, 0, stream>>>(hs, bucket, off2, dinv, b1, a1, N);

    // layer 2
    gemm_mfma_kernel<1, true><<<(N + 63) / 64, 256, 0, stream>>>(a1, Wt2, dinv, hs2, N);
    agg2_kernel<<<N, 64, 0, stream>>>(hs2, bucket, off2, dinv, b2, out, N);
}